// Round 4
// baseline (163.310 us; speedup 1.0000x reference)
//
#include <hip/hip_runtime.h>
#include <hip/hip_bf16.h>
#include <math.h>

// ---------------------------------------------------------------------------
// SupConLoss on MI355X.
// out = 0.5*CE(predicts,targets) + 0.5*nt_xent(Anorm, temp=0.1)
//       + 0.25*nt_xent2(Anorm, temp=0.05)
// Round 4: symmetric fused GEMM + register-direct stats epilogue.
// 528 upper-triangular 128x128 tiles; stats reduced from MFMA accumulators
// via __shfl_xor (A-side: lanes 0-3 bits = cols; B-side: lane bits 4-5 +
// regs = rows). Only 4 KB LDS for half-combine -> ~21.5 KB total LDS,
// restoring 4 blocks/CU occupancy lost in round 3.
// Exp sums unshifted (|exponent|<=20 safe in fp32); reference's row-max
// shift for S_j applied exactly in merge: S_j = s2_raw * exp(-max2_j).
// ---------------------------------------------------------------------------

typedef __attribute__((ext_vector_type(8))) short bf16x8;
typedef __attribute__((ext_vector_type(4))) float f32x4;

__device__ __forceinline__ float blockReduceSum(float v, float* sbuf) {
#pragma unroll
  for (int o = 32; o > 0; o >>= 1) v += __shfl_down(v, o, 64);
  int lane = threadIdx.x & 63;
  int w = threadIdx.x >> 6;
  __syncthreads();
  if (lane == 0) sbuf[w] = v;
  __syncthreads();
  return sbuf[0] + sbuf[1] + sbuf[2] + sbuf[3];
}

// --- 1. fused normalize (bf16 out) + per-row CE ----------------------------
__global__ void k_prep(const float* __restrict__ X, const float* __restrict__ P,
                       const int* __restrict__ tgt,
                       unsigned short* __restrict__ Ab,
                       float* __restrict__ ce_row, int D, int C) {
  __shared__ float sbuf[8];
  int row = blockIdx.x;
  const float* x = X + (size_t)row * D;
  unsigned short* a = Ab + (size_t)row * D;
  float ss = 0.f;
  for (int j = threadIdx.x; j < D; j += blockDim.x) {
    float v = x[j];
    ss += v * v;
  }
  ss = blockReduceSum(ss, sbuf);
  float inv = 1.0f / fmaxf(sqrtf(ss), 1e-12f);
  for (int j = threadIdx.x; j < D; j += blockDim.x) {
    union { __hip_bfloat16 h; unsigned short u; } cv;
    cv.h = __float2bfloat16(x[j] * inv);
    a[j] = cv.u;
  }
  if (threadIdx.x == 0) {
    const float* p = P + (size_t)row * C;
    float m = -INFINITY;
    for (int c = 0; c < C; ++c) m = fmaxf(m, p[c]);
    float s = 0.f;
    for (int c = 0; c < C; ++c) s += expf(p[c] - m);
    int t = tgt[row];
    ce_row[row] = -(p[t] - m - logf(s));
  }
}

// --- 2. fused symmetric GEMM + register-direct stats -----------------------
// part layout: float4 part[N][NB]; (psum, s1_raw, s2_raw, max2).
__global__ __launch_bounds__(256, 4) void k_gemm_fused(
    const unsigned short* __restrict__ A, const int* __restrict__ lab,
    float4* __restrict__ part, int N, int K, int NB) {
  __shared__ unsigned short Asm[128 * 32];   // 8 KB
  __shared__ unsigned short Bsm[128 * 32];   // 8 KB
  __shared__ float4 red[256];                // 4 KB (epilogue half-combine)
  __shared__ int labR[128];
  __shared__ int labC[128];

  // triangular decode: bid -> (by, bx), by >= bx
  int bid = blockIdx.x;
  int by = (int)((sqrtf(8.f * (float)bid + 1.f) - 1.f) * 0.5f);
  while ((by + 1) * (by + 2) / 2 <= bid) ++by;
  while (by * (by + 1) / 2 > bid) --by;
  int bx = bid - by * (by + 1) / 2;

  const int t = threadIdx.x;
  const int lane = t & 63;
  const int w = t >> 6;
  const int rowBase = by * 128;
  const int colBase = bx * 128;
  const int wr = (w >> 1) * 64;
  const int wc = (w & 1) * 64;

  if (t < 128) labR[t] = lab[rowBase + t];
  else labC[t - 128] = lab[colBase + (t - 128)];

  f32x4 acc[4][4] = {};
  const int sr = t >> 2;
  const int sc = (t & 3) * 8;

  for (int k0 = 0; k0 < K; k0 += 32) {
#pragma unroll
    for (int p = 0; p < 2; ++p) {
      const unsigned short* ga =
          A + (size_t)(rowBase + p * 64 + sr) * K + k0 + sc;
      __builtin_amdgcn_global_load_lds(
          (const __attribute__((address_space(1))) unsigned int*)ga,
          (__attribute__((address_space(3))) unsigned int*)&Asm[p * 2048 +
                                                                t * 8],
          16, 0, 0);
      const unsigned short* gb =
          A + (size_t)(colBase + p * 64 + sr) * K + k0 + sc;
      __builtin_amdgcn_global_load_lds(
          (const __attribute__((address_space(1))) unsigned int*)gb,
          (__attribute__((address_space(3))) unsigned int*)&Bsm[p * 2048 +
                                                                t * 8],
          16, 0, 0);
    }
    __syncthreads();
    bf16x8 af[4], bf[4];
#pragma unroll
    for (int mt = 0; mt < 4; ++mt)
      af[mt] = *(const bf16x8*)&Asm[(wr + mt * 16 + (lane & 15)) * 32 +
                                    (lane >> 4) * 8];
#pragma unroll
    for (int nt = 0; nt < 4; ++nt)
      bf[nt] = *(const bf16x8*)&Bsm[(wc + nt * 16 + (lane & 15)) * 32 +
                                    (lane >> 4) * 8];
#pragma unroll
    for (int mt = 0; mt < 4; ++mt)
#pragma unroll
      for (int nt = 0; nt < 4; ++nt)
        acc[mt][nt] = __builtin_amdgcn_mfma_f32_16x16x32_bf16(
            af[mt], bf[nt], acc[mt][nt], 0, 0, 0);
    __syncthreads();
  }

  // ---- epilogue: register-direct stats -----------------------------------
  // element (tile-local): row = wr + mt*16 + (lane>>4)*4 + r
  //                       col = wc + nt*16 + (lane&15)
  int rl[4][4], cl[4];
#pragma unroll
  for (int mt = 0; mt < 4; ++mt)
#pragma unroll
    for (int r = 0; r < 4; ++r)
      rl[mt][r] = labR[wr + mt * 16 + (lane >> 4) * 4 + r];
#pragma unroll
  for (int nt = 0; nt < 4; ++nt) cl[nt] = labC[wc + nt * 16 + (lane & 15)];
  const bool dg = (by == bx);

  // A-side: per-row stats over this block's 128 cols.
#pragma unroll
  for (int mt = 0; mt < 4; ++mt) {
#pragma unroll
    for (int r = 0; r < 4; ++r) {
      int rowL = wr + mt * 16 + (lane >> 4) * 4 + r;
      int lr = rl[mt][r];
      float ps = 0.f, s1 = 0.f, s2 = 0.f, m2 = -1e30f;
#pragma unroll
      for (int nt = 0; nt < 4; ++nt) {
        float v = acc[mt][nt][r];
        int colL = wc + nt * 16 + (lane & 15);
        bool diag = dg && (rowL == colL);
        bool same = (lr == cl[nt]);
        float v20 = v * 20.f;
        s1 += __expf(diag ? 0.f : v * 10.f);
        ps += (same && !diag) ? v : 0.f;
        s2 += same ? 0.f : __expf(v20);
        m2 = same ? m2 : fmaxf(m2, v20);
      }
#pragma unroll
      for (int o = 1; o < 16; o <<= 1) {
        ps += __shfl_xor(ps, o, 64);
        s1 += __shfl_xor(s1, o, 64);
        s2 += __shfl_xor(s2, o, 64);
        m2 = fmaxf(m2, __shfl_xor(m2, o, 64));
      }
      if ((lane & 15) == 0) red[rowL * 2 + (w & 1)] = make_float4(ps, s1, s2, m2);
    }
  }
  __syncthreads();
  if (t < 128) {
    float4 a = red[t * 2], b = red[t * 2 + 1];
    part[(size_t)(rowBase + t) * NB + bx] =
        make_float4(a.x + b.x, a.y + b.y, a.z + b.z, fmaxf(a.w, b.w));
  }

  // B-side (transposed): per-col stats over this block's 128 rows.
  // Only for off-diagonal blocks (diagonal block's A-side covers all).
  if (by != bx) {
    __syncthreads();  // protect red reuse
#pragma unroll
    for (int nt = 0; nt < 4; ++nt) {
      int colL = wc + nt * 16 + (lane & 15);
      int lc = cl[nt];
      float ps = 0.f, s1 = 0.f, s2 = 0.f, m2 = -1e30f;
#pragma unroll
      for (int mt = 0; mt < 4; ++mt)
#pragma unroll
        for (int r = 0; r < 4; ++r) {
          float v = acc[mt][nt][r];
          bool same = (rl[mt][r] == lc);
          float v20 = v * 20.f;
          s1 += __expf(v * 10.f);
          ps += same ? v : 0.f;
          s2 += same ? 0.f : __expf(v20);
          m2 = same ? m2 : fmaxf(m2, v20);
        }
#pragma unroll
      for (int o = 16; o < 64; o <<= 1) {
        ps += __shfl_xor(ps, o, 64);
        s1 += __shfl_xor(s1, o, 64);
        s2 += __shfl_xor(s2, o, 64);
        m2 = fmaxf(m2, __shfl_xor(m2, o, 64));
      }
      if ((lane >> 4) == 0)
        red[colL * 2 + (w >> 1)] = make_float4(ps, s1, s2, m2);
    }
    __syncthreads();
    if (t < 128) {
      float4 a = red[t * 2], b = red[t * 2 + 1];
      part[(size_t)(colBase + t) * NB + by] =
          make_float4(a.x + b.x, a.y + b.y, a.z + b.z, fmaxf(a.w, b.w));
    }
  }
}

// --- 3. merge partials per row --------------------------------------------
__global__ void k_merge(const float4* __restrict__ part,
                        float* __restrict__ psumRow,
                        float* __restrict__ logS1, float* __restrict__ Srow,
                        int N, int NB) {
  int lane = threadIdx.x & 63;
  int w = threadIdx.x >> 6;
  int row = blockIdx.x * 4 + w;
  float ps = 0.f, s1 = 0.f, s2 = 0.f, m2 = -1e30f;
  if (lane < NB) {
    float4 p = part[(size_t)row * NB + lane];
    ps = p.x; s1 = p.y; s2 = p.z; m2 = p.w;
  }
#pragma unroll
  for (int o = 16; o > 0; o >>= 1) {
    ps += __shfl_down(ps, o, 64);
    s1 += __shfl_down(s1, o, 64);
    s2 += __shfl_down(s2, o, 64);
    m2 = fmaxf(m2, __shfl_down(m2, o, 64));
  }
  if (lane == 0) {
    psumRow[row] = ps;
    logS1[row] = logf(s1);
    Srow[row] = (m2 < -1e29f) ? 0.f : s2 * expf(-m2);
  }
}

// --- 4. finalize ----------------------------------------------------------
__global__ void k_final(const float* __restrict__ ce_row,
                        const float* __restrict__ psumRow,
                        const float* __restrict__ logS1,
                        const float* __restrict__ Srow,
                        const int* __restrict__ lab, float* __restrict__ out,
                        int N, int C) {
  __shared__ float classS[32];
  __shared__ int classCnt[32];
  __shared__ float sbuf[8];
  if (threadIdx.x < 32) {
    classS[threadIdx.x] = 0.f;
    classCnt[threadIdx.x] = 0;
  }
  __syncthreads();
  float sumCe = 0.f;
  for (int i = threadIdx.x; i < N; i += blockDim.x) {
    sumCe += ce_row[i];
    int l = lab[i];
    atomicAdd(&classCnt[l], 1);
    atomicAdd(&classS[l], Srow[i]);
  }
  __syncthreads();
  float sumP1 = 0.f;
  for (int i = threadIdx.x; i < N; i += blockDim.x) {
    int l = lab[i];
    int pc = classCnt[l] - 1;
    if (pc > 0) sumP1 += psumRow[i] * 10.f / (float)pc - logS1[i];
  }
  sumCe = blockReduceSum(sumCe, sbuf);
  sumP1 = blockReduceSum(sumP1, sbuf);
  if (threadIdx.x == 0) {
    float totS = 0.f;
    for (int c = 0; c < C; ++c) totS += classS[c];
    float l2sum = 0.f;
    for (int c = 0; c < C; ++c) {
      int cnt = classCnt[c];
      if (cnt >= 2) {
        float negs = (float)(N - cnt);
        float x = (totS - classS[c]) / negs;
        l2sum += (float)cnt * logf(x + 1e-12f);
      }
    }
    float ce = sumCe / (float)N;
    float ntx1 = -sumP1 / (float)N;
    float ntx2 = l2sum / (float)N;
    out[0] = 0.5f * ce + 0.5f * ntx1 + 0.25f * ntx2;
  }
}

extern "C" void kernel_launch(void* const* d_in, const int* in_sizes, int n_in,
                              void* d_out, int out_size, void* d_ws,
                              size_t ws_size, hipStream_t stream) {
  const float* X = (const float*)d_in[0];  // cls_feats [N,D]
  const float* P = (const float*)d_in[1];  // predicts  [N,C]
  const int* tgt = (const int*)d_in[2];    // targets   [N]
  float* out = (float*)d_out;

  int N = in_sizes[2];
  int D = in_sizes[0] / N;
  int C = in_sizes[1] / N;
  int NB = N / 128;

  char* ws = (char*)d_ws;
  unsigned short* Ab = (unsigned short*)ws;          // N*D bf16
  float4* part = (float4*)(ws + (size_t)N * D * 2);  // N*NB float4
  float* ce_row = (float*)((char*)part + (size_t)N * NB * 16);
  float* psumRow = ce_row + N;
  float* logS1 = psumRow + N;
  float* Srow = logS1 + N;

  k_prep<<<N, 256, 0, stream>>>(X, P, tgt, Ab, ce_row, D, C);
  int nblk = NB * (NB + 1) / 2;
  k_gemm_fused<<<nblk, 256, 0, stream>>>(Ab, tgt, part, N, D, NB);
  k_merge<<<N / 4, 256, 0, stream>>>(part, psumRow, logS1, Srow, N, NB);
  k_final<<<1, 256, 0, stream>>>(ce_row, psumRow, logS1, Srow, tgt, out, N, C);
}